// Round 2
// baseline (4364.181 us; speedup 1.0000x reference)
//
#include <hip/hip_runtime.h>
#include <cstdint>
#include <cstddef>

#define B_   256
#define T_   512
#define E_   128
#define H_   256
#define G3   768

typedef _Float16 f16x8 __attribute__((ext_vector_type(8)));
typedef _Float16 f16x4 __attribute__((ext_vector_type(4)));
typedef float    f32x4 __attribute__((ext_vector_type(4)));

__device__ __forceinline__ float sigm(float x) { return 1.f / (1.f + __expf(-x)); }
__device__ __forceinline__ float tanh_(float x) {
  x = fminf(15.f, fmaxf(-15.f, x));
  float e = __expf(2.f * x);
  return (e - 1.f) / (e + 1.f);
}

// ---------------- prep: swizzle weights into MFMA B-fragment order (fp16) + bias vectors ----
// WSW[dir][kc(12)][tile(48)][lane(64)][8]  fp16. kc 0..7: W_hh (K=256), kc 8..11: W_ih (K=128).
// B-frag for tile nt: lane l supplies B[k=(l>>4)*8+j][n=l&15] = W[nt*16+(l&15)][k] -> 8 consecutive
// fp32 in the ORIGINAL row-major weight layout. 1 KB per (kc,tile) block, coalesced wave loads.
// BIAS[dir][4][256]: 0: b_ih_r+b_hh_r, 1: b_ih_z+b_hh_z, 2: b_ih_n, 3: b_hh_n (kept apart: b_hh_n
// sits inside r*(...) per PyTorch GRU).
__global__ __launch_bounds__(256) void prep_kernel(
    const float* __restrict__ whhf, const float* __restrict__ whhb,
    const float* __restrict__ wihf, const float* __restrict__ wihb,
    const float* __restrict__ bihf, const float* __restrict__ bhhf,
    const float* __restrict__ bihb, const float* __restrict__ bhhb,
    _Float16* __restrict__ WSW, float* __restrict__ BIAS)
{
  int idx = blockIdx.x * 256 + threadIdx.x;
  if (idx < 73728) {                          // 2*12*48*64
    int lane = idx & 63;
    int tile = (idx >> 6) % 48;
    int kc   = (idx / 3072) % 12;
    int dir  = idx / 36864;
    int ncol = tile * 16 + (lane & 15);
    int quad = lane >> 4;
    const float* src;
    if (kc < 8) {
      const float* w = dir ? whhb : whhf;     // [768][256] row-major
      src = w + (size_t)ncol * H_ + kc * 32 + quad * 8;
    } else {
      const float* w = dir ? wihb : wihf;     // [768][128] row-major
      src = w + (size_t)ncol * E_ + (kc - 8) * 32 + quad * 8;
    }
    f16x8 v;
    #pragma unroll
    for (int j = 0; j < 8; ++j) v[j] = (_Float16)src[j];
    *(f16x8*)(WSW + (size_t)idx * 8) = v;
  } else if (idx < 73728 + 2048) {
    int i2 = idx - 73728;
    int d = i2 >> 10, kind = (i2 >> 8) & 3, j = i2 & 255;
    const float* bih = d ? bihb : bihf;
    const float* bhh = d ? bhhb : bhhf;
    float v;
    if      (kind == 0) v = bih[j] + bhh[j];
    else if (kind == 1) v = bih[H_ + j] + bhh[H_ + j];
    else if (kind == 2) v = bih[2 * H_ + j];
    else                v = bhh[2 * H_ + j];
    BIAS[d * 1024 + kind * 256 + j] = v;
  }
}

// ---------------- rank batch rows by length (desc) so blocks get uniform-length groups -------
__global__ void sort_kernel(const int* __restrict__ lens, int* __restrict__ order)
{
  int i = threadIdx.x;                        // one block of 256
  int li = lens[i];
  int rank = 0;
  for (int k = 0; k < B_; ++k) {
    int lk = lens[k];
    rank += (lk > li) || (lk == li && k < i);
  }
  order[rank] = i;
}

// ---------------- fused GRU scan: 32 blocks (2 dirs x 16 groups), 16 chains/block, fp16 MFMA --
// Per step: D[16 chains][768 gates] = h(fp16,LDS) @ Whh^T  +  x_t(fp16,LDS) @ Wih^T, weights
// streamed from L2 in B-frag order. Wave w owns units [32w,32w+32): r tiles {2w,2w+1},
// z {16+2w,17+2w}, n {32+2w,33+2w} -> epilogue is wave-local. One barrier per step.
__global__ __launch_bounds__(512, 2) void scan_kernel(
    const _Float16* __restrict__ WSW, const float* __restrict__ BIAS,
    const int* __restrict__ seqs, const float* __restrict__ embed,
    const int* __restrict__ lens, const int* __restrict__ order,
    float* __restrict__ hcat)
{
  __shared__ _Float16 hf[2][16][264];         // +8 pad: A-frag ds_read_b128 ~2-way banks (free)
  __shared__ float    h32[2][16][260];        // fp32 master copy of h
  __shared__ _Float16 xs[2][16][136];         // staged x_t (fp16)
  __shared__ int s_row[16], s_len[16];

  const int dir = blockIdx.x & 1, grp = blockIdx.x >> 1;
  const int tid = threadIdx.x;
  const int w = tid >> 6, lane = tid & 63, lm = lane & 15, lq = lane >> 4;

  if (tid < 16) { int r = order[grp * 16 + tid]; s_row[tid] = r; s_len[tid] = lens[r]; }
  for (int i = tid; i < 16 * 264; i += 512) ((_Float16*)hf[0])[i]  = (_Float16)0.f;
  for (int i = tid; i < 16 * 260; i += 512) ((float*)h32[0])[i] = 0.f;
  __syncthreads();

  int ml = 1;
  #pragma unroll
  for (int i = 0; i < 16; ++i) ml = max(ml, s_len[i]);

  const int srow16 = tid >> 5, sq = tid & 31;           // x-staging: 32 threads per chain
  const int rowb = s_row[srow16], lenr = s_len[srow16];

  { // stage x(0) into xs[0]
    int p = dir ? (lenr - 1) : 0;
    p = min(max(p, 0), T_ - 1);
    int tok = seqs[(size_t)rowb * T_ + p];
    float4 f = *(const float4*)(embed + (size_t)tok * E_ + sq * 4);
    f16x4 h4; h4[0] = (_Float16)f.x; h4[1] = (_Float16)f.y; h4[2] = (_Float16)f.z; h4[3] = (_Float16)f.w;
    *(f16x4*)(&xs[0][srow16][sq * 4]) = h4;
  }

  int len_e[4];
  #pragma unroll
  for (int i = 0; i < 4; ++i) len_e[i] = s_len[lq * 4 + i];
  float b_r[2], b_z[2], b_nx[2], b_nh[2];
  #pragma unroll
  for (int th = 0; th < 2; ++th) {
    int u = w * 32 + th * 16 + lm;
    b_r[th]  = BIAS[dir * 1024 + 0 * 256 + u];
    b_z[th]  = BIAS[dir * 1024 + 1 * 256 + u];
    b_nx[th] = BIAS[dir * 1024 + 2 * 256 + u];
    b_nh[th] = BIAS[dir * 1024 + 3 * 256 + u];
  }
  int tiles[6];
  tiles[0] = 2 * w;      tiles[1] = 2 * w + 1;
  tiles[2] = 16 + 2 * w; tiles[3] = 17 + 2 * w;
  tiles[4] = 32 + 2 * w; tiles[5] = 33 + 2 * w;
  const _Float16* wbase = WSW + (size_t)dir * 294912 + lane * 8;  // dir block = 12*24576 halfs

  f32x4 ar[2] = {}, az[2] = {}, anh[2] = {}, anx[2] = {};
  int cur = 0;
  __syncthreads();                                       // xs[0] staged, s_* visible

  for (int t = 0; t < ml; ++t) {
    const int nxt = cur ^ 1;
    { // stage x(t+1) into xs[nxt]; loads overlap the MFMA stream below
      int p = dir ? (lenr - 2 - t) : (t + 1);
      p = min(max(p, 0), T_ - 1);
      int tok = seqs[(size_t)rowb * T_ + p];
      float4 f = *(const float4*)(embed + (size_t)tok * E_ + sq * 4);
      f16x4 h4; h4[0] = (_Float16)f.x; h4[1] = (_Float16)f.y; h4[2] = (_Float16)f.z; h4[3] = (_Float16)f.w;
      *(f16x4*)(&xs[nxt][srow16][sq * 4]) = h4;
    }
    f16x8 bc[6], bn[6];
    #pragma unroll
    for (int i = 0; i < 6; ++i)
      bc[i] = *(const f16x8*)(wbase + tiles[i] * 512);
    #pragma unroll
    for (int kc = 0; kc < 12; ++kc) {
      if (kc < 11) {
        #pragma unroll
        for (int i = 0; i < 6; ++i)
          bn[i] = *(const f16x8*)(wbase + (kc + 1) * 24576 + tiles[i] * 512);
      }
      f16x8 a;
      if (kc < 8) a = *(const f16x8*)(&hf[cur][lm][kc * 32 + lq * 8]);
      else        a = *(const f16x8*)(&xs[cur][lm][(kc - 8) * 32 + lq * 8]);
      ar[0] = __builtin_amdgcn_mfma_f32_16x16x32_f16(a, bc[0], ar[0], 0, 0, 0);
      ar[1] = __builtin_amdgcn_mfma_f32_16x16x32_f16(a, bc[1], ar[1], 0, 0, 0);
      az[0] = __builtin_amdgcn_mfma_f32_16x16x32_f16(a, bc[2], az[0], 0, 0, 0);
      az[1] = __builtin_amdgcn_mfma_f32_16x16x32_f16(a, bc[3], az[1], 0, 0, 0);
      if (kc < 8) {
        anh[0] = __builtin_amdgcn_mfma_f32_16x16x32_f16(a, bc[4], anh[0], 0, 0, 0);
        anh[1] = __builtin_amdgcn_mfma_f32_16x16x32_f16(a, bc[5], anh[1], 0, 0, 0);
      } else {
        anx[0] = __builtin_amdgcn_mfma_f32_16x16x32_f16(a, bc[4], anx[0], 0, 0, 0);
        anx[1] = __builtin_amdgcn_mfma_f32_16x16x32_f16(a, bc[5], anx[1], 0, 0, 0);
      }
      #pragma unroll
      for (int i = 0; i < 6; ++i) bc[i] = bn[i];
    }
    // epilogue (wave-local: own units only). D layout: chain=(lane>>4)*4+reg, unit-col=lane&15.
    #pragma unroll
    for (int th = 0; th < 2; ++th) {
      int u = w * 32 + th * 16 + lm;
      #pragma unroll
      for (int i = 0; i < 4; ++i) {
        int c = lq * 4 + i;
        float r = sigm(ar[th][i] + b_r[th]);
        float z = sigm(az[th][i] + b_z[th]);
        float n = tanh_(anx[th][i] + b_nx[th] + r * (anh[th][i] + b_nh[th]));
        float ho = h32[cur][c][u];
        float hn = (t < len_e[i]) ? ((1.f - z) * n + z * ho) : ho;  // freeze past len
        h32[nxt][c][u] = hn;
        hf[nxt][c][u]  = (_Float16)hn;
      }
    }
    #pragma unroll
    for (int th = 0; th < 2; ++th) {
      ar[th] = (f32x4){0.f, 0.f, 0.f, 0.f};
      az[th] = (f32x4){0.f, 0.f, 0.f, 0.f};
      anh[th] = (f32x4){0.f, 0.f, 0.f, 0.f};
      anx[th] = (f32x4){0.f, 0.f, 0.f, 0.f};
    }
    __syncthreads();
    cur = nxt;
  }
  #pragma unroll
  for (int j = 0; j < 8; ++j)
    hcat[(size_t)rowb * (2 * H_) + dir * H_ + sq * 8 + j] = h32[cur][srow16][sq * 8 + j];
}

// ---------------- final FC: out[b][c] = hcat[b] . W_fc[c] + b_fc[c] ----------------
__global__ __launch_bounds__(512) void fc_kernel(
    const float* __restrict__ hcat, const float* __restrict__ wfc,
    const float* __restrict__ bfc, float* __restrict__ out)
{
  const int b = blockIdx.x, t = threadIdx.x;
  float h  = hcat[(size_t)b * 512 + t];
  float p0 = h * wfc[t];
  float p1 = h * wfc[512 + t];
  #pragma unroll
  for (int off = 32; off > 0; off >>= 1) {
    p0 += __shfl_down(p0, off);
    p1 += __shfl_down(p1, off);
  }
  __shared__ float s0[8], s1[8];
  if ((t & 63) == 0) { s0[t >> 6] = p0; s1[t >> 6] = p1; }
  __syncthreads();
  if (t == 0) {
    float a = bfc[0], c = bfc[1];
    #pragma unroll
    for (int i = 0; i < 8; ++i) { a += s0[i]; c += s1[i]; }
    out[b * 2 + 0] = a;
    out[b * 2 + 1] = c;
  }
}

extern "C" void kernel_launch(void* const* d_in, const int* in_sizes, int n_in,
                              void* d_out, int out_size, void* d_ws, size_t ws_size,
                              hipStream_t stream)
{
  (void)in_sizes; (void)n_in; (void)out_size; (void)ws_size;
  const int*   seqs  = (const int*)d_in[0];
  const int*   lens  = (const int*)d_in[1];
  const float* embed = (const float*)d_in[2];
  const float* wihf  = (const float*)d_in[3];
  const float* whhf  = (const float*)d_in[4];
  const float* bihf  = (const float*)d_in[5];
  const float* bhhf  = (const float*)d_in[6];
  const float* wihb  = (const float*)d_in[7];
  const float* whhb  = (const float*)d_in[8];
  const float* bihb  = (const float*)d_in[9];
  const float* bhhb  = (const float*)d_in[10];
  const float* wfc   = (const float*)d_in[11];
  const float* bfc   = (const float*)d_in[12];
  float* out = (float*)d_out;

  // workspace layout (~1.72 MB total — tiny, safe)
  char* ws = (char*)d_ws;
  _Float16* WSW = (_Float16*)ws;                         // 2*12*48*64*8 halfs = 1,179,648 B
  size_t off = 1179648;
  float* BIAS = (float*)(ws + off);  off += 2048 * 4;    // 8,192 B
  float* HCAT = (float*)(ws + off);  off += (size_t)B_ * 2 * H_ * 4;  // 524,288 B
  int* ORDER  = (int*)(ws + off);                        // 1,024 B

  prep_kernel<<<296, 256, 0, stream>>>(whhf, whhb, wihf, wihb,
                                       bihf, bhhf, bihb, bhhb, WSW, BIAS);
  sort_kernel<<<1, 256, 0, stream>>>(lens, ORDER);
  scan_kernel<<<32, 512, 0, stream>>>(WSW, BIAS, seqs, embed, lens, ORDER, HCAT);
  fc_kernel<<<B_, 512, 0, stream>>>(HCAT, wfc, bfc, out);
}

// Round 4
// 1571.049 us; speedup vs baseline: 2.7779x; 2.7779x over previous
//
#include <hip/hip_runtime.h>
#include <cstdint>
#include <cstddef>

#define B_   256
#define T_   512
#define E_   128
#define H_   256
#define G3   768

typedef _Float16 f16x8 __attribute__((ext_vector_type(8)));
typedef _Float16 f16x4 __attribute__((ext_vector_type(4)));
typedef float    f32x4 __attribute__((ext_vector_type(4)));

__device__ __forceinline__ float sigm(float x) { return 1.f / (1.f + __expf(-x)); }
__device__ __forceinline__ float tanh_(float x) {
  x = fminf(15.f, fmaxf(-15.f, x));
  float e = __expf(2.f * x);
  return (e - 1.f) / (e + 1.f);
}

// ---------------- prep: swizzle weights into MFMA B-fragment order (fp16) + bias vectors ----
// WSW[dir][kc(12)][tile(48)][lane(64)][8]  fp16. kc 0..7: W_hh (K=256), kc 8..11: W_ih (K=128).
// Tiles: 0..15 = r (unit = tile*16+col), 16..31 = z, 32..47 = n.
// BIAS[dir][4][256]: 0: b_ih_r+b_hh_r, 1: b_ih_z+b_hh_z, 2: b_ih_n, 3: b_hh_n.
__global__ __launch_bounds__(256) void prep_kernel(
    const float* __restrict__ whhf, const float* __restrict__ whhb,
    const float* __restrict__ wihf, const float* __restrict__ wihb,
    const float* __restrict__ bihf, const float* __restrict__ bhhf,
    const float* __restrict__ bihb, const float* __restrict__ bhhb,
    _Float16* __restrict__ WSW, float* __restrict__ BIAS)
{
  int idx = blockIdx.x * 256 + threadIdx.x;
  if (idx < 73728) {                          // 2*12*48*64
    int lane = idx & 63;
    int tile = (idx >> 6) % 48;
    int kc   = (idx / 3072) % 12;
    int dir  = idx / 36864;
    int ncol = tile * 16 + (lane & 15);
    int quad = lane >> 4;
    const float* src;
    if (kc < 8) {
      const float* w = dir ? whhb : whhf;     // [768][256] row-major
      src = w + (size_t)ncol * H_ + kc * 32 + quad * 8;
    } else {
      const float* w = dir ? wihb : wihf;     // [768][128] row-major
      src = w + (size_t)ncol * E_ + (kc - 8) * 32 + quad * 8;
    }
    f16x8 v;
    #pragma unroll
    for (int j = 0; j < 8; ++j) v[j] = (_Float16)src[j];
    *(f16x8*)(WSW + (size_t)idx * 8) = v;
  } else if (idx < 73728 + 2048) {
    int i2 = idx - 73728;
    int d = i2 >> 10, kind = (i2 >> 8) & 3, j = i2 & 255;
    const float* bih = d ? bihb : bihf;
    const float* bhh = d ? bhhb : bhhf;
    float v;
    if      (kind == 0) v = bih[j] + bhh[j];
    else if (kind == 1) v = bih[H_ + j] + bhh[H_ + j];
    else if (kind == 2) v = bih[2 * H_ + j];
    else                v = bhh[2 * H_ + j];
    BIAS[d * 1024 + kind * 256 + j] = v;
  }
}

// ------- rank rows by length (desc) + zero the sync flags (ws is 0xAA-poisoned each call) ----
__global__ void sort_kernel(const int* __restrict__ lens, int* __restrict__ order,
                            int* __restrict__ flags)
{
  int i = threadIdx.x;                        // one block of 256
  for (int k = i; k < 1024; k += 256) flags[k] = 0;
  int li = lens[i];
  int rank = 0;
  for (int k = 0; k < B_; ++k) {
    int lk = lens[k];
    rank += (lk > li) || (lk == li && k < i);
  }
  order[rank] = i;
}

// ---------------- fused GRU scan: 64 blocks = 32 groups (2 dir x 16 chain-grps) x 2 subs -----
// Weights live ENTIRELY in VGPRs: wave w of block sub owns units [128*sub+16w, +16):
// r-tile 8*sub+w, z-tile 16+.., n-tile 32+.. -> 36 f16x8 = 144 VGPRs, loaded once.
// Per step: gates = h(LDS)@Whh^T + x(LDS)@Wih^T via MFMA; epilogue in-registers; 4 KB h-slice
// exchanged with the single peer block via agent-scope (sc1) stores/loads + step-counter flag.
// Slices are LOCAL-unit indexed [0,128) on both writer and reader (R3 bug: writer used the
// GLOBAL unit id -> sub=1 wrote 4 KB past its slice, clobbering neighbors -> absmax 1.2e-2).
// Double-buffered slices: overwrite of buf[t&1] happens at t+2, which requires peer flag >=
// t+2, which requires the peer to have READ buf[t&1] at step t -> race-free.
__global__ __launch_bounds__(512, 2) void scan_kernel(
    const _Float16* __restrict__ WSW, const float* __restrict__ BIAS,
    const int* __restrict__ seqs, const float* __restrict__ embed,
    const int* __restrict__ lens, const int* __restrict__ order,
    _Float16* __restrict__ HX, int* __restrict__ FLAGS,
    float* __restrict__ hcat)
{
  __shared__ __align__(16) _Float16 hbuf[2][16][264];   // [buf][chain][unit], +8 pad
  __shared__ __align__(16) _Float16 xsb[2][16][136];    // [buf][chain][k]
  __shared__ int s_row[16], s_len[16];

  const int g = blockIdx.x & 31, sub = blockIdx.x >> 5;
  const int dir = g & 1, grp = g >> 1;
  const int tid = threadIdx.x;
  const int w = tid >> 6, lane = tid & 63, lm = lane & 15, lq = lane >> 4;

  if (tid < 16) { int r = order[grp * 16 + tid]; s_row[tid] = r; s_len[tid] = lens[r]; }
  for (int i = tid; i < 2 * 16 * 264; i += 512) ((_Float16*)hbuf)[i] = (_Float16)0.f;
  __syncthreads();

  int ml = 1;
  #pragma unroll
  for (int i = 0; i < 16; ++i) ml = max(ml, s_len[i]);

  // ---- x staging ids: 32 threads per chain, 4 floats each ----
  const int xchain = tid >> 5, xq = tid & 31;
  const int rowb = s_row[xchain], lenr = s_len[xchain];
  { // stage x(0)
    int p = dir ? (lenr - 1) : 0;
    p = min(max(p, 0), T_ - 1);
    int tok = seqs[(size_t)rowb * T_ + p];
    float4 f = *(const float4*)(embed + (size_t)tok * E_ + xq * 4);
    f16x4 h4; h4[0] = (_Float16)f.x; h4[1] = (_Float16)f.y; h4[2] = (_Float16)f.z; h4[3] = (_Float16)f.w;
    *(f16x4*)(&xsb[0][xchain][xq * 4]) = h4;
  }

  // ---- load loop-invariant weights into registers (36 x f16x8 = 144 VGPRs) ----
  const int t_r = 8 * sub + w;
  const _Float16* wb = WSW + (size_t)dir * 294912 + (size_t)lane * 8;
  f16x8 wr_[12], wz_[12], wn_[12];
  #pragma unroll
  for (int kc = 0; kc < 12; ++kc) {
    wr_[kc] = *(const f16x8*)(wb + (size_t)kc * 24576 + (t_r)      * 512);
    wz_[kc] = *(const f16x8*)(wb + (size_t)kc * 24576 + (16 + t_r) * 512);
    wn_[kc] = *(const f16x8*)(wb + (size_t)kc * 24576 + (32 + t_r) * 512);
  }

  const int ulocal = 16 * w + lm;             // unit index within this block's 128-slice
  const int u = 128 * sub + ulocal;           // global unit id
  const float b_r  = BIAS[dir * 1024 +          u];
  const float b_z  = BIAS[dir * 1024 + 256 +    u];
  const float b_nx = BIAS[dir * 1024 + 512 +    u];
  const float b_nh = BIAS[dir * 1024 + 768 +    u];
  int len_e[4];
  #pragma unroll
  for (int i = 0; i < 4; ++i) len_e[i] = s_len[lq * 4 + i];
  float h32r[4] = {0.f, 0.f, 0.f, 0.f};

  // ---- exchange buffers: HX slice = [local unit(128)][chain(16)] fp16 = 4 KB ----
  _Float16* hx_own[2]; const _Float16* hx_peer[2];
  #pragma unroll
  for (int b = 0; b < 2; ++b) {
    hx_own[b]  = HX + (size_t)(g * 4 + b * 2 + sub)       * 2048;
    hx_peer[b] = HX + (size_t)(g * 4 + b * 2 + (1 - sub)) * 2048;
  }
  int* flag_own        = FLAGS + (g * 2 + sub) * 16;        // 64B-padded slots
  const int* flag_peer = FLAGS + (g * 2 + (1 - sub)) * 16;
  const int pbase = 128 * (1 - sub);

  int cur = 0;
  __syncthreads();

  for (int t = 0; t < ml; ++t) {
    const int nxt = cur ^ 1;
    // A: prefetch x(t+1) into registers (independent of MFMA chain)
    int p = dir ? (lenr - 2 - t) : (t + 1);
    p = min(max(p, 0), T_ - 1);
    int tok = seqs[(size_t)rowb * T_ + p];
    float4 xf = *(const float4*)(embed + (size_t)tok * E_ + xq * 4);

    // B: gates from register weights
    f32x4 ar = {}, az = {}, anx = {}, anh = {};
    #pragma unroll
    for (int kc = 0; kc < 8; ++kc) {
      f16x8 a = *(const f16x8*)(&hbuf[cur][lm][kc * 32 + lq * 8]);
      ar  = __builtin_amdgcn_mfma_f32_16x16x32_f16(a, wr_[kc], ar,  0, 0, 0);
      az  = __builtin_amdgcn_mfma_f32_16x16x32_f16(a, wz_[kc], az,  0, 0, 0);
      anh = __builtin_amdgcn_mfma_f32_16x16x32_f16(a, wn_[kc], anh, 0, 0, 0);
    }
    #pragma unroll
    for (int kc = 0; kc < 4; ++kc) {
      f16x8 a = *(const f16x8*)(&xsb[cur][lm][kc * 32 + lq * 8]);
      ar  = __builtin_amdgcn_mfma_f32_16x16x32_f16(a, wr_[8 + kc], ar,  0, 0, 0);
      az  = __builtin_amdgcn_mfma_f32_16x16x32_f16(a, wz_[8 + kc], az,  0, 0, 0);
      anx = __builtin_amdgcn_mfma_f32_16x16x32_f16(a, wn_[8 + kc], anx, 0, 0, 0);
    }

    // epilogue: D layout chain=(lane>>4)*4+i, unit-col=lane&15 (all wave-local)
    union { f16x4 h; unsigned long long q; } pk;
    #pragma unroll
    for (int i = 0; i < 4; ++i) {
      float r = sigm(ar[i] + b_r);
      float z = sigm(az[i] + b_z);
      float n = tanh_(anx[i] + b_nx + r * (anh[i] + b_nh));
      float hn = (t < len_e[i]) ? ((1.f - z) * n + z * h32r[i]) : h32r[i];
      h32r[i] = hn;
      pk.h[i] = (_Float16)hn;
      hbuf[nxt][lq * 4 + i][u] = pk.h[i];              // own units into next h-buffer
    }
    // C: coherent (agent) store of own slice at LOCAL unit index
    __hip_atomic_store((unsigned long long*)(hx_own[t & 1] + ulocal * 16 + lq * 4), pk.q,
                       __ATOMIC_RELAXED, __HIP_MEMORY_SCOPE_AGENT);
    // D: stage x(t+1)
    { f16x4 h4; h4[0] = (_Float16)xf.x; h4[1] = (_Float16)xf.y; h4[2] = (_Float16)xf.z; h4[3] = (_Float16)xf.w;
      *(f16x4*)(&xsb[nxt][xchain][xq * 4]) = h4; }

    __syncthreads();                                   // drains vmcnt: slice globally visible
    if (tid == 0) {
      __hip_atomic_store(flag_own, t + 1, __ATOMIC_RELEASE, __HIP_MEMORY_SCOPE_AGENT);
      while (__hip_atomic_load(flag_peer, __ATOMIC_ACQUIRE, __HIP_MEMORY_SCOPE_AGENT) <= t) {}
    }
    __syncthreads();

    // H: pull peer's 128 units for this step (agent-scope loads bypass stale local caches)
    { int unit = tid >> 2, cq = tid & 3;
      unsigned long long v = __hip_atomic_load(
          (const unsigned long long*)(hx_peer[t & 1] + unit * 16 + cq * 4),
          __ATOMIC_RELAXED, __HIP_MEMORY_SCOPE_AGENT);
      union { f16x4 h; unsigned long long q; } pv; pv.q = v;
      #pragma unroll
      for (int j = 0; j < 4; ++j) hbuf[nxt][cq * 4 + j][pbase + unit] = pv.h[j];
    }
    __syncthreads();
    cur = nxt;
  }

  // final hidden -> hcat[row][dir*256 + u]
  #pragma unroll
  for (int i = 0; i < 4; ++i) {
    int row = s_row[lq * 4 + i];
    hcat[(size_t)row * (2 * H_) + dir * H_ + u] = h32r[i];
  }
}

// ---------------- final FC: out[b][c] = hcat[b] . W_fc[c] + b_fc[c] ----------------
__global__ __launch_bounds__(512) void fc_kernel(
    const float* __restrict__ hcat, const float* __restrict__ wfc,
    const float* __restrict__ bfc, float* __restrict__ out)
{
  const int b = blockIdx.x, t = threadIdx.x;
  float h  = hcat[(size_t)b * 512 + t];
  float p0 = h * wfc[t];
  float p1 = h * wfc[512 + t];
  #pragma unroll
  for (int off = 32; off > 0; off >>= 1) {
    p0 += __shfl_down(p0, off);
    p1 += __shfl_down(p1, off);
  }
  __shared__ float s0[8], s1[8];
  if ((t & 63) == 0) { s0[t >> 6] = p0; s1[t >> 6] = p1; }
  __syncthreads();
  if (t == 0) {
    float a = bfc[0], c = bfc[1];
    #pragma unroll
    for (int i = 0; i < 8; ++i) { a += s0[i]; c += s1[i]; }
    out[b * 2 + 0] = a;
    out[b * 2 + 1] = c;
  }
}

extern "C" void kernel_launch(void* const* d_in, const int* in_sizes, int n_in,
                              void* d_out, int out_size, void* d_ws, size_t ws_size,
                              hipStream_t stream)
{
  (void)in_sizes; (void)n_in; (void)out_size; (void)ws_size;
  const int*   seqs  = (const int*)d_in[0];
  const int*   lens  = (const int*)d_in[1];
  const float* embed = (const float*)d_in[2];
  const float* wihf  = (const float*)d_in[3];
  const float* whhf  = (const float*)d_in[4];
  const float* bihf  = (const float*)d_in[5];
  const float* bhhf  = (const float*)d_in[6];
  const float* wihb  = (const float*)d_in[7];
  const float* whhb  = (const float*)d_in[8];
  const float* bihb  = (const float*)d_in[9];
  const float* bhhb  = (const float*)d_in[10];
  const float* wfc   = (const float*)d_in[11];
  const float* bfc   = (const float*)d_in[12];
  float* out = (float*)d_out;

  // workspace layout (~2.24 MB)
  char* ws = (char*)d_ws;
  _Float16* WSW = (_Float16*)ws;                         // 1,179,648 B
  size_t off = 1179648;
  float* BIAS = (float*)(ws + off);  off += 8192;
  float* HCAT = (float*)(ws + off);  off += (size_t)B_ * 2 * H_ * 4;   // 524,288
  int* ORDER  = (int*)(ws + off);    off += 1024;
  int* FLAGS  = (int*)(ws + off);    off += 4096;        // 64 slots x 64 B padding
  _Float16* HX = (_Float16*)(ws + off);                  // 128 slices x 4 KB = 524,288 B

  prep_kernel<<<296, 256, 0, stream>>>(whhf, whhb, wihf, wihb,
                                       bihf, bhhf, bihb, bhhb, WSW, BIAS);
  sort_kernel<<<1, 256, 0, stream>>>(lens, ORDER, FLAGS);
  scan_kernel<<<64, 512, 0, stream>>>(WSW, BIAS, seqs, embed, lens, ORDER,
                                      HX, FLAGS, HCAT);
  fc_kernel<<<B_, 512, 0, stream>>>(HCAT, wfc, bfc, out);
}